// Round 4
// baseline (566.529 us; speedup 1.0000x reference)
//
#include <hip/hip_runtime.h>
#include <hip/hip_bf16.h>

#define LL 512
#define CC 128
#define MM (LL*LL)   // 262144 positions

typedef __attribute__((ext_vector_type(8))) short bf16x8;
typedef __attribute__((ext_vector_type(4))) float f32x4;
using bf16 = __hip_bfloat16;

__device__ __forceinline__ unsigned short f2bfbits(float f) {
    bf16 h = __float2bfloat16(f);
    return *reinterpret_cast<unsigned short*>(&h);
}
__device__ __forceinline__ float bfbits2f(unsigned short b) {
    union { unsigned int u; float f; } cv; cv.u = ((unsigned int)b) << 16; return cv.f;
}
__device__ __forceinline__ void storeT(float* p, float v) { *p = v; }
__device__ __forceinline__ void storeT(bf16* p, float v) { *p = __float2bfloat16(v); }
__device__ __forceinline__ float4 load4(const float* p) { return *(const float4*)p; }
__device__ __forceinline__ float4 load4(const bf16* p) {
    ushort4 u = *(const ushort4*)p;
    float4 f;
    f.x = bfbits2f(u.x); f.y = bfbits2f(u.y);
    f.z = bfbits2f(u.z); f.w = bfbits2f(u.w);
    return f;
}

// sigmoid-gate: v * sigmoid(g), with v_rcp_f32 instead of the ~10-instr
// IEEE divide sequence (rcp ~1ulp; downstream rounds to bf16/fp32 — safe).
__device__ __forceinline__ float sig_gate(float g, float v) {
    return v * __builtin_amdgcn_rcpf(1.f + __expf(-g));
}

// stage 8 consecutive fp32 elements into bf16 LDS (16B dst)
__device__ __forceinline__ void stage8(const float* src, bf16* dst) {
    float4 f0 = *(const float4*)(src);
    float4 f1 = *(const float4*)(src + 4);
    union { ushort4 v; unsigned short u[4]; } a, b;
    a.u[0] = f2bfbits(f0.x); a.u[1] = f2bfbits(f0.y);
    a.u[2] = f2bfbits(f0.z); a.u[3] = f2bfbits(f0.w);
    b.u[0] = f2bfbits(f1.x); b.u[1] = f2bfbits(f1.y);
    b.u[2] = f2bfbits(f1.z); b.u[3] = f2bfbits(f1.w);
    *(ushort4*)(dst)     = a.v;
    *(ushort4*)(dst + 4) = b.v;
}

// raw prefetch holder: load global fp32 early, convert/commit to LDS late
struct Raw8F {
    float4 a, b;
    __device__ __forceinline__ void load(const float* p) {
        a = *(const float4*)p; b = *(const float4*)(p + 4);
    }
    __device__ __forceinline__ void commit(bf16* d) const {
        union { ushort4 v; unsigned short u[4]; } x, y;
        x.u[0] = f2bfbits(a.x); x.u[1] = f2bfbits(a.y);
        x.u[2] = f2bfbits(a.z); x.u[3] = f2bfbits(a.w);
        y.u[0] = f2bfbits(b.x); y.u[1] = f2bfbits(b.y);
        y.u[2] = f2bfbits(b.z); y.u[3] = f2bfbits(b.w);
        *(ushort4*)(d)     = x.v;
        *(ushort4*)(d + 4) = y.v;
    }
};

// ---------------------------------------------------------------------------
// K0: convert six 128x128 fp32 weight matrices to bf16 in ws.
// ---------------------------------------------------------------------------
__global__ __launch_bounds__(256) void cvt_w_kernel(
    const float* __restrict__ s0, const float* __restrict__ s1,
    const float* __restrict__ s2, const float* __restrict__ s3,
    const float* __restrict__ s4, const float* __restrict__ s5,
    bf16* __restrict__ dst)
{
    const float* srcs[6] = {s0, s1, s2, s3, s4, s5};
    const float* s = srcs[blockIdx.y];
    bf16* d = dst + blockIdx.y * (CC * CC);
    int i = (blockIdx.x * 256 + threadIdx.x) * 4;
    float4 f = *(const float4*)(s + i);
    union { ushort4 v; unsigned short u[4]; } p;
    p.u[0] = f2bfbits(f.x); p.u[1] = f2bfbits(f.y);
    p.u[2] = f2bfbits(f.z); p.u[3] = f2bfbits(f.w);
    *(ushort4*)(d + i) = p.v;
}

// ---------------------------------------------------------------------------
// K1: FUSED dual-sided projection (left AND right) — x read ONCE.
// 512 threads = 8 waves. Waves 0-3: sigmoid(xWl1+bl1)*(xWl2+bl2) -> OUTL^T;
// waves 4-7: same with Wr1/Wr2 -> OUTR^T. (R6 structure, proven <115us.)
// ---------------------------------------------------------------------------
__global__ __launch_bounds__(512, 2) void proj_lr_kernel(
    const float* __restrict__ X, const bf16* __restrict__ Wb,
    const float* __restrict__ Bl1, const float* __restrict__ Bl2,
    const float* __restrict__ Br1, const float* __restrict__ Br2,
    bf16* __restrict__ OUTL, bf16* __restrict__ OUTR)
{
    __shared__ bf16 xs[2][64][136];       // +8 bf16 pad: 272B row stride
    const int t = threadIdx.x;
    const int wave = t >> 6, lane = t & 63;
    const int grp = wave >> 2;            // 0 = left, 1 = right
    const int w4 = wave & 3;
    const int lrow = lane & 15, lq = lane >> 4;
    const int n0 = w4 * 32 + lrow;

    const bf16* W1 = Wb + (grp ? 2 * CC * CC : 0);
    const bf16* W2 = W1 + CC * CC;
    const float* B1 = grp ? Br1 : Bl1;
    const float* B2 = grp ? Br2 : Bl2;
    bf16* OUT = grp ? OUTR : OUTL;

    bf16x8 wf1[2][4], wf2[2][4];          // [nt_local][k0/32]
    float bias1[2], bias2[2];
    #pragma unroll
    for (int nl = 0; nl < 2; ++nl) {
        const int n = n0 + nl * 16;
        bias1[nl] = B1[n]; bias2[nl] = B2[n];
        #pragma unroll
        for (int kk = 0; kk < 4; ++kk) {
            wf1[nl][kk] = *(const bf16x8*)(W1 + n * CC + kk * 32 + lq * 8);
            wf2[nl][kk] = *(const bf16x8*)(W2 + n * CC + kk * 32 + lq * 8);
        }
    }

    constexpr int T = 4;
    const size_t block_row0 = (size_t)blockIdx.x * (64 * T);

    // stage tile 0 directly (8192 elements / 512 threads = 2 chunks of 8)
    #pragma unroll
    for (int it = 0; it < 2; ++it) {
        int chunk = it * 512 + t;
        int r = chunk >> 4, o = (chunk & 15) << 3;
        stage8(X + (block_row0 + r) * CC + o, &xs[0][r][o]);
    }

    #pragma unroll
    for (int tt = 0; tt < T; ++tt) {
        const size_t row0 = block_row0 + (size_t)tt * 64;
        const int cur = tt & 1;

        __syncthreads();   // xs[cur] staged; xs[cur^1] readers done

        // issue next tile's loads AFTER the barrier: they stay in flight
        // through MFMA + epilogue; vmcnt wait lands at commit() below.
        Raw8F pf[2];
        if (tt + 1 < T) {
            #pragma unroll
            for (int it = 0; it < 2; ++it) {
                int chunk = it * 512 + t;
                int r = chunk >> 4, o = (chunk & 15) << 3;
                pf[it].load(X + (row0 + 64 + r) * CC + o);
            }
        }

        f32x4 acc1[2][4], acc2[2][4];     // [nt_local][mt]
        const f32x4 z = {0.f, 0.f, 0.f, 0.f};
        #pragma unroll
        for (int nl = 0; nl < 2; ++nl)
            #pragma unroll
            for (int mt = 0; mt < 4; ++mt) { acc1[nl][mt] = z; acc2[nl][mt] = z; }

        #pragma unroll
        for (int kk = 0; kk < 4; ++kk) {
            bf16x8 a[4];
            #pragma unroll
            for (int mt = 0; mt < 4; ++mt)
                a[mt] = *(const bf16x8*)(&xs[cur][mt * 16 + lrow][kk * 32 + lq * 8]);
            #pragma unroll
            for (int nl = 0; nl < 2; ++nl)
                #pragma unroll
                for (int mt = 0; mt < 4; ++mt) {
                    acc1[nl][mt] = __builtin_amdgcn_mfma_f32_16x16x32_bf16(
                        a[mt], wf1[nl][kk], acc1[nl][mt], 0, 0, 0);
                    acc2[nl][mt] = __builtin_amdgcn_mfma_f32_16x16x32_bf16(
                        a[mt], wf2[nl][kk], acc2[nl][mt], 0, 0, 0);
                }
        }

        // epilogue: transposed bf16 store. C/D: col=lane&15 (n), row=lq*4+reg (m)
        #pragma unroll
        for (int nl = 0; nl < 2; ++nl) {
            const int n = n0 + nl * 16;
            #pragma unroll
            for (int mt = 0; mt < 4; ++mt) {
                const size_t m0 = row0 + mt * 16 + lq * 4;
                union { ushort4 v; unsigned short u[4]; } pk;
                #pragma unroll
                for (int r = 0; r < 4; ++r) {
                    float p1 = acc1[nl][mt][r] + bias1[nl];
                    float p2 = acc2[nl][mt][r] + bias2[nl];
                    pk.u[r] = f2bfbits(sig_gate(p1, p2));
                }
                *(ushort4*)(OUT + (size_t)n * MM + m0) = pk.v;
            }
        }

        // commit prefetched tile LAST: maximizes load-latency cover.
        if (tt + 1 < T) {
            #pragma unroll
            for (int it = 0; it < 2; ++it) {
                int chunk = it * 512 + t;
                int r = chunk >> 4, o = (chunk & 15) << 3;
                pf[it].commit(&xs[cur ^ 1][r][o]);
            }
        }
    }
}

// ---------------------------------------------------------------------------
// K2: per-channel batched GEMM  tri[c] = L_c (512x512) @ R_c^T (512x512)
// R7: single LDS buffer, TWO barriers per K-step (round-3 lesson: the
// lockstep cadence IS the L2/L3 locality — dbuf desync inflated FETCH
// 199->244MB). Load latency hidden via register prefetch that fits inside
// the lockstep: ds_write(regs) ; barrier ; issue loads k+1 ; MFMA ; barrier.
// The k+1 loads drain at barrier-2 (after MFMA), not exposed between
// barriers as in round-0.
// Guards: FETCH ~199MB (244 => desync returned), WRITE ~131MB.
// ---------------------------------------------------------------------------
template<typename TriT>
__global__ __launch_bounds__(256) void tri_mm_kernel(
    const bf16* __restrict__ Lt, const bf16* __restrict__ Rt,
    TriT* __restrict__ tri)
{
    __shared__ bf16 As[128][40];          // +8 bf16 pad: 80B row stride
    __shared__ bf16 Bs[128][40];
    const int c  = blockIdx.z;
    const int i0 = blockIdx.x * 128, j0 = blockIdx.y * 128;
    const bf16* Lb = Lt + (size_t)c * MM;
    const bf16* Rb = Rt + (size_t)c * MM;

    const int t    = threadIdx.x;
    const int wave = t >> 6, lane = t & 63;
    const int lrow = lane & 15, lq = lane >> 4;
    const int wi = (wave & 1) * 64, wj = (wave >> 1) * 64;

    f32x4 acc[4][4];
    const f32x4 z = {0.f, 0.f, 0.f, 0.f};
    #pragma unroll
    for (int mt = 0; mt < 4; ++mt)
        #pragma unroll
        for (int nt = 0; nt < 4; ++nt) acc[mt][nt] = z;

    // prologue: K-slice 0 into prefetch regs
    uint4 pfa[2], pfb[2];
    #pragma unroll
    for (int it = 0; it < 2; ++it) {
        int chunk = it * 256 + t;
        int r = chunk >> 2, o = (chunk & 3) << 3;
        pfa[it] = *(const uint4*)(Lb + (size_t)(i0 + r) * LL + o);
        pfb[it] = *(const uint4*)(Rb + (size_t)(j0 + r) * LL + o);
    }

    for (int ks = 0; ks < 16; ++ks) {
        // commit prefetched K-slice to LDS (vmcnt waits here, not exposed:
        // loads were issued a full MFMA phase ago)
        #pragma unroll
        for (int it = 0; it < 2; ++it) {
            int chunk = it * 256 + t;
            int r = chunk >> 2, o = (chunk & 3) << 3;
            *(uint4*)(&As[r][o]) = pfa[it];
            *(uint4*)(&Bs[r][o]) = pfb[it];
        }
        __syncthreads();   // barrier 1: LDS published, lockstep point A

        // issue k+1 loads: in flight during ds_read + MFMA, drained at
        // barrier 2 (after compute) — latency covered, cadence preserved.
        if (ks + 1 < 16) {
            const int k0 = (ks + 1) * 32;
            #pragma unroll
            for (int it = 0; it < 2; ++it) {
                int chunk = it * 256 + t;
                int r = chunk >> 2, o = (chunk & 3) << 3;
                pfa[it] = *(const uint4*)(Lb + (size_t)(i0 + r) * LL + k0 + o);
                pfb[it] = *(const uint4*)(Rb + (size_t)(j0 + r) * LL + k0 + o);
            }
        }

        bf16x8 af[4], bfr[4];
        #pragma unroll
        for (int mt = 0; mt < 4; ++mt)
            af[mt] = *(const bf16x8*)(&As[wi + mt * 16 + lrow][lq * 8]);
        #pragma unroll
        for (int nt = 0; nt < 4; ++nt)
            bfr[nt] = *(const bf16x8*)(&Bs[wj + nt * 16 + lrow][lq * 8]);
        #pragma unroll
        for (int mt = 0; mt < 4; ++mt)
            #pragma unroll
            for (int nt = 0; nt < 4; ++nt)
                acc[mt][nt] = __builtin_amdgcn_mfma_f32_16x16x32_bf16(
                    af[mt], bfr[nt], acc[mt][nt], 0, 0, 0);

        __syncthreads();   // barrier 2: reads done, lockstep point B
    }

    TriT* triC = tri + (size_t)c * MM;
    #pragma unroll
    for (int mt = 0; mt < 4; ++mt) {
        #pragma unroll
        for (int nt = 0; nt < 4; ++nt) {
            const int ib = i0 + wi + mt * 16 + lq * 4;
            const int j  = j0 + wj + nt * 16 + lrow;
            #pragma unroll
            for (int r = 0; r < 4; ++r)
                storeT(&triC[(size_t)(ib + r) * LL + j], acc[mt][nt][r]);
        }
    }
}

// ---------------------------------------------------------------------------
// K3: FUSED LayerNorm + output gating. (R6 structure, proven <115us.)
// ---------------------------------------------------------------------------
template<typename TriT>
__global__ __launch_bounds__(256, 2) void ln_gate_kernel(
    const TriT* __restrict__ tri,
    const float* __restrict__ G, const float* __restrict__ Bt,
    const bf16* __restrict__ W1, const float* __restrict__ B1,
    const bf16* __restrict__ W2, const float* __restrict__ B2,
    float* __restrict__ OUT)
{
    __shared__ float s[128][68];          // tri tile [c][p], 272B row stride
    __shared__ bf16 xs[64][136];          // normalized bf16 tile [p][c]
    __shared__ float part[2][4][64];
    __shared__ float mu[64], rsd[64];
    __shared__ float gs[128], bs[128];

    const int t = threadIdx.x;
    const int wave = t >> 6, lane = t & 63;
    const int lrow = lane & 15, lq = lane >> 4;
    const int n0 = wave * 32 + lrow;

    if (t < 128) { gs[t] = G[t]; bs[t] = Bt[t]; }

    bf16x8 wf1[2][4], wf2[2][4];
    float bias1[2], bias2[2];
    #pragma unroll
    for (int nl = 0; nl < 2; ++nl) {
        const int n = n0 + nl * 16;
        bias1[nl] = B1[n]; bias2[nl] = B2[n];
        #pragma unroll
        for (int kk = 0; kk < 4; ++kk) {
            wf1[nl][kk] = *(const bf16x8*)(W1 + n * CC + kk * 32 + lq * 8);
            wf2[nl][kk] = *(const bf16x8*)(W2 + n * CC + kk * 32 + lq * 8);
        }
    }

    constexpr int T = 4;
    const size_t bp0 = (size_t)blockIdx.x * (64 * T);

    // prologue: stage tri tile 0 (128c x 64p fp32 -> s)
    #pragma unroll
    for (int it = 0; it < 8; ++it) {
        int idx = it * 256 + t;
        int cc = idx >> 4, p4 = (idx & 15) << 2;
        float4 f = load4(tri + (size_t)cc * MM + bp0 + p4);
        *(float4*)(&s[cc][p4]) = f;
    }

    for (int tt = 0; tt < T; ++tt) {
        const size_t p0 = bp0 + (size_t)tt * 64;

        float4 pf[8];
        if (tt + 1 < T) {
            #pragma unroll
            for (int it = 0; it < 8; ++it) {
                int idx = it * 256 + t;
                int cc = idx >> 4, p4 = (idx & 15) << 2;
                pf[it] = load4(tri + (size_t)cc * MM + p0 + 64 + p4);
            }
        }
        __syncthreads();   // (a) s staged (prologue or prev commit); gs/bs ready

        // LN stats: wave w sums channels [w*32, w*32+32) at position=lane
        float sum = 0.f, sq = 0.f;
        #pragma unroll 8
        for (int cc = wave * 32; cc < wave * 32 + 32; ++cc) {
            float v = s[cc][lane]; sum += v; sq += v * v;
        }
        part[0][wave][lane] = sum; part[1][wave][lane] = sq;
        __syncthreads();   // (b)
        if (t < 64) {
            float S = part[0][0][t] + part[0][1][t] + part[0][2][t] + part[0][3][t];
            float Q = part[1][0][t] + part[1][1][t] + part[1][2][t] + part[1][3][t];
            float m = S * (1.f / 128.f);
            float var = Q * (1.f / 128.f) - m * m;
            mu[t] = m; rsd[t] = rsqrtf(var + 1e-5f);
        }
        __syncthreads();   // (c)

        // normalize -> xs bf16. p = lane (conflict-free s reads), c8 uniform.
        #pragma unroll
        for (int it = 0; it < 4; ++it) {
            int chunk = it * 256 + t;
            int p = chunk & 63, c8 = (chunk >> 6) << 3;
            float m = mu[p], r = rsd[p];
            union { uint4 v; unsigned short u[8]; } pk;
            #pragma unroll
            for (int jj = 0; jj < 8; ++jj) {
                int cc = c8 + jj;
                pk.u[jj] = f2bfbits((s[cc][p] - m) * r * gs[cc] + bs[cc]);
            }
            *(uint4*)(&xs[p][c8]) = pk.v;
        }
        __syncthreads();   // (d) xs ready; all s reads done

        if (tt + 1 < T) {
            #pragma unroll
            for (int it = 0; it < 8; ++it) {
                int idx = it * 256 + t;
                int cc = idx >> 4, p4 = (idx & 15) << 2;
                *(float4*)(&s[cc][p4]) = pf[it];
            }
        }

        f32x4 acc1[2][4], acc2[2][4];
        const f32x4 z = {0.f, 0.f, 0.f, 0.f};
        #pragma unroll
        for (int nl = 0; nl < 2; ++nl)
            #pragma unroll
            for (int mt = 0; mt < 4; ++mt) { acc1[nl][mt] = z; acc2[nl][mt] = z; }

        #pragma unroll
        for (int kk = 0; kk < 4; ++kk) {
            bf16x8 a[4];
            #pragma unroll
            for (int mt = 0; mt < 4; ++mt)
                a[mt] = *(const bf16x8*)(&xs[mt * 16 + lrow][kk * 32 + lq * 8]);
            #pragma unroll
            for (int nl = 0; nl < 2; ++nl)
                #pragma unroll
                for (int mt = 0; mt < 4; ++mt) {
                    acc1[nl][mt] = __builtin_amdgcn_mfma_f32_16x16x32_bf16(
                        a[mt], wf1[nl][kk], acc1[nl][mt], 0, 0, 0);
                    acc2[nl][mt] = __builtin_amdgcn_mfma_f32_16x16x32_bf16(
                        a[mt], wf2[nl][kk], acc2[nl][mt], 0, 0, 0);
                }
        }

        // epilogue: fp32 out [M][128]
        #pragma unroll
        for (int nl = 0; nl < 2; ++nl) {
            const int n = n0 + nl * 16;
            #pragma unroll
            for (int mt = 0; mt < 4; ++mt) {
                const size_t m0 = p0 + mt * 16 + lq * 4;
                #pragma unroll
                for (int r = 0; r < 4; ++r) {
                    float p1 = acc1[nl][mt][r] + bias1[nl];
                    float p2 = acc2[nl][mt][r] + bias2[nl];
                    OUT[(m0 + r) * CC + n] = sig_gate(p1, p2);
                }
            }
        }
    }
}

// ---------------------------------------------------------------------------
extern "C" void kernel_launch(void* const* d_in, const int* in_sizes, int n_in,
                              void* d_out, int out_size, void* d_ws, size_t ws_size,
                              hipStream_t stream)
{
    const float* x   = (const float*)d_in[0];
    const float* Wl1 = (const float*)d_in[1];
    const float* bl1 = (const float*)d_in[2];
    const float* Wl2 = (const float*)d_in[3];
    const float* bl2 = (const float*)d_in[4];
    const float* Wr1 = (const float*)d_in[5];
    const float* br1 = (const float*)d_in[6];
    const float* Wr2 = (const float*)d_in[7];
    const float* br2 = (const float*)d_in[8];
    const float* Wg  = (const float*)d_in[9];
    const float* bg  = (const float*)d_in[10];
    const float* Wo  = (const float*)d_in[11];
    const float* bo  = (const float*)d_in[12];
    const float* lng = (const float*)d_in[13];
    const float* lnb = (const float*)d_in[14];
    float* out = (float*)d_out;

    char* ws = (char*)d_ws;
    bf16* left_t  = (bf16*)(ws);                        // 64 MiB bf16 [128][M]
    bf16* right_t = (bf16*)(ws + (64ull << 20));        // 64 MiB bf16 [128][M]
    bf16* Wb      = (bf16*)(ws + (128ull << 20));       // 192 KiB: 6 bf16 weights
    void* tri     = (void*)(ws + (132ull << 20));       // 128 MiB fp32 / 64 MiB bf16

    const bool tri_fp32 = (ws_size >= (260ull << 20));

    bf16* Wbg = Wb + 4 * CC * CC;
    bf16* Wbo = Wb + 5 * CC * CC;

    dim3 blk(256);
    cvt_w_kernel<<<dim3(16, 6), blk, 0, stream>>>(Wl1, Wl2, Wr1, Wr2, Wg, Wo, Wb);
    proj_lr_kernel<<<dim3(MM / 256), dim3(512), 0, stream>>>(
        x, Wb, bl1, bl2, br1, br2, left_t, right_t);
    if (tri_fp32) {
        tri_mm_kernel<float><<<dim3(4, 4, 128), blk, 0, stream>>>(left_t, right_t, (float*)tri);
        ln_gate_kernel<float><<<dim3(MM / 256), blk, 0, stream>>>(
            (const float*)tri, lng, lnb, Wbg, bg, Wbo, bo, out);
    } else {
        tri_mm_kernel<bf16><<<dim3(4, 4, 128), blk, 0, stream>>>(left_t, right_t, (bf16*)tri);
        ln_gate_kernel<bf16><<<dim3(MM / 256), blk, 0, stream>>>(
            (const bf16*)tri, lng, lnb, Wbg, bg, Wbo, bo, out);
    }
}

// Round 5
// 452.381 us; speedup vs baseline: 1.2523x; 1.2523x over previous
//
#include <hip/hip_runtime.h>
#include <hip/hip_bf16.h>

#define LL 512
#define CC 128
#define MM (LL*LL)   // 262144 positions

typedef __attribute__((ext_vector_type(8))) short bf16x8;
typedef __attribute__((ext_vector_type(4))) float f32x4;
using bf16 = __hip_bfloat16;

__device__ __forceinline__ unsigned short f2bfbits(float f) {
    bf16 h = __float2bfloat16(f);
    return *reinterpret_cast<unsigned short*>(&h);
}
__device__ __forceinline__ float bfbits2f(unsigned short b) {
    union { unsigned int u; float f; } cv; cv.u = ((unsigned int)b) << 16; return cv.f;
}
__device__ __forceinline__ void storeT(float* p, float v) { *p = v; }
__device__ __forceinline__ void storeT(bf16* p, float v) { *p = __float2bfloat16(v); }
__device__ __forceinline__ float4 load4(const float* p) { return *(const float4*)p; }
__device__ __forceinline__ float4 load4(const bf16* p) {
    ushort4 u = *(const ushort4*)p;
    float4 f;
    f.x = bfbits2f(u.x); f.y = bfbits2f(u.y);
    f.z = bfbits2f(u.z); f.w = bfbits2f(u.w);
    return f;
}

// sigmoid-gate: v * sigmoid(g), with v_rcp_f32 instead of the ~10-instr
// IEEE divide sequence (rcp ~1ulp; downstream rounds to bf16/fp32 — safe).
__device__ __forceinline__ float sig_gate(float g, float v) {
    return v * __builtin_amdgcn_rcpf(1.f + __expf(-g));
}

// stage 8 consecutive fp32 elements into bf16 LDS (16B dst)
__device__ __forceinline__ void stage8(const float* src, bf16* dst) {
    float4 f0 = *(const float4*)(src);
    float4 f1 = *(const float4*)(src + 4);
    union { ushort4 v; unsigned short u[4]; } a, b;
    a.u[0] = f2bfbits(f0.x); a.u[1] = f2bfbits(f0.y);
    a.u[2] = f2bfbits(f0.z); a.u[3] = f2bfbits(f0.w);
    b.u[0] = f2bfbits(f1.x); b.u[1] = f2bfbits(f1.y);
    b.u[2] = f2bfbits(f1.z); b.u[3] = f2bfbits(f1.w);
    *(ushort4*)(dst)     = a.v;
    *(ushort4*)(dst + 4) = b.v;
}

// raw prefetch holder: load global fp32 early, convert/commit to LDS late
struct Raw8F {
    float4 a, b;
    __device__ __forceinline__ void load(const float* p) {
        a = *(const float4*)p; b = *(const float4*)(p + 4);
    }
    __device__ __forceinline__ void commit(bf16* d) const {
        union { ushort4 v; unsigned short u[4]; } x, y;
        x.u[0] = f2bfbits(a.x); x.u[1] = f2bfbits(a.y);
        x.u[2] = f2bfbits(a.z); x.u[3] = f2bfbits(a.w);
        y.u[0] = f2bfbits(b.x); y.u[1] = f2bfbits(b.y);
        y.u[2] = f2bfbits(b.z); y.u[3] = f2bfbits(b.w);
        *(ushort4*)(d)     = x.v;
        *(ushort4*)(d + 4) = y.v;
    }
};

// ---------------------------------------------------------------------------
// K0: convert six 128x128 fp32 weight matrices to bf16 in ws.
// ---------------------------------------------------------------------------
__global__ __launch_bounds__(256) void cvt_w_kernel(
    const float* __restrict__ s0, const float* __restrict__ s1,
    const float* __restrict__ s2, const float* __restrict__ s3,
    const float* __restrict__ s4, const float* __restrict__ s5,
    bf16* __restrict__ dst)
{
    const float* srcs[6] = {s0, s1, s2, s3, s4, s5};
    const float* s = srcs[blockIdx.y];
    bf16* d = dst + blockIdx.y * (CC * CC);
    int i = (blockIdx.x * 256 + threadIdx.x) * 4;
    float4 f = *(const float4*)(s + i);
    union { ushort4 v; unsigned short u[4]; } p;
    p.u[0] = f2bfbits(f.x); p.u[1] = f2bfbits(f.y);
    p.u[2] = f2bfbits(f.z); p.u[3] = f2bfbits(f.w);
    *(ushort4*)(d + i) = p.v;
}

// ---------------------------------------------------------------------------
// K1: FUSED dual-sided projection (left AND right) — x read ONCE.
// 512 threads = 8 waves. Waves 0-3: sigmoid(xWl1+bl1)*(xWl2+bl2) -> OUTL^T;
// waves 4-7: same with Wr1/Wr2 -> OUTR^T. (R6 structure, kept.)
// ---------------------------------------------------------------------------
__global__ __launch_bounds__(512, 2) void proj_lr_kernel(
    const float* __restrict__ X, const bf16* __restrict__ Wb,
    const float* __restrict__ Bl1, const float* __restrict__ Bl2,
    const float* __restrict__ Br1, const float* __restrict__ Br2,
    bf16* __restrict__ OUTL, bf16* __restrict__ OUTR)
{
    __shared__ bf16 xs[2][64][136];       // +8 bf16 pad: 272B row stride
    const int t = threadIdx.x;
    const int wave = t >> 6, lane = t & 63;
    const int grp = wave >> 2;            // 0 = left, 1 = right
    const int w4 = wave & 3;
    const int lrow = lane & 15, lq = lane >> 4;
    const int n0 = w4 * 32 + lrow;

    const bf16* W1 = Wb + (grp ? 2 * CC * CC : 0);
    const bf16* W2 = W1 + CC * CC;
    const float* B1 = grp ? Br1 : Bl1;
    const float* B2 = grp ? Br2 : Bl2;
    bf16* OUT = grp ? OUTR : OUTL;

    bf16x8 wf1[2][4], wf2[2][4];          // [nt_local][k0/32]
    float bias1[2], bias2[2];
    #pragma unroll
    for (int nl = 0; nl < 2; ++nl) {
        const int n = n0 + nl * 16;
        bias1[nl] = B1[n]; bias2[nl] = B2[n];
        #pragma unroll
        for (int kk = 0; kk < 4; ++kk) {
            wf1[nl][kk] = *(const bf16x8*)(W1 + n * CC + kk * 32 + lq * 8);
            wf2[nl][kk] = *(const bf16x8*)(W2 + n * CC + kk * 32 + lq * 8);
        }
    }

    constexpr int T = 4;
    const size_t block_row0 = (size_t)blockIdx.x * (64 * T);

    // stage tile 0 directly (8192 elements / 512 threads = 2 chunks of 8)
    #pragma unroll
    for (int it = 0; it < 2; ++it) {
        int chunk = it * 512 + t;
        int r = chunk >> 4, o = (chunk & 15) << 3;
        stage8(X + (block_row0 + r) * CC + o, &xs[0][r][o]);
    }

    #pragma unroll
    for (int tt = 0; tt < T; ++tt) {
        const size_t row0 = block_row0 + (size_t)tt * 64;
        const int cur = tt & 1;

        __syncthreads();   // xs[cur] staged; xs[cur^1] readers done

        // issue next tile's loads AFTER the barrier: they stay in flight
        // through MFMA + epilogue; vmcnt wait lands at commit() below.
        Raw8F pf[2];
        if (tt + 1 < T) {
            #pragma unroll
            for (int it = 0; it < 2; ++it) {
                int chunk = it * 512 + t;
                int r = chunk >> 4, o = (chunk & 15) << 3;
                pf[it].load(X + (row0 + 64 + r) * CC + o);
            }
        }

        f32x4 acc1[2][4], acc2[2][4];     // [nt_local][mt]
        const f32x4 z = {0.f, 0.f, 0.f, 0.f};
        #pragma unroll
        for (int nl = 0; nl < 2; ++nl)
            #pragma unroll
            for (int mt = 0; mt < 4; ++mt) { acc1[nl][mt] = z; acc2[nl][mt] = z; }

        #pragma unroll
        for (int kk = 0; kk < 4; ++kk) {
            bf16x8 a[4];
            #pragma unroll
            for (int mt = 0; mt < 4; ++mt)
                a[mt] = *(const bf16x8*)(&xs[cur][mt * 16 + lrow][kk * 32 + lq * 8]);
            #pragma unroll
            for (int nl = 0; nl < 2; ++nl)
                #pragma unroll
                for (int mt = 0; mt < 4; ++mt) {
                    acc1[nl][mt] = __builtin_amdgcn_mfma_f32_16x16x32_bf16(
                        a[mt], wf1[nl][kk], acc1[nl][mt], 0, 0, 0);
                    acc2[nl][mt] = __builtin_amdgcn_mfma_f32_16x16x32_bf16(
                        a[mt], wf2[nl][kk], acc2[nl][mt], 0, 0, 0);
                }
        }

        // epilogue: transposed bf16 store. C/D: col=lane&15 (n), row=lq*4+reg (m)
        #pragma unroll
        for (int nl = 0; nl < 2; ++nl) {
            const int n = n0 + nl * 16;
            #pragma unroll
            for (int mt = 0; mt < 4; ++mt) {
                const size_t m0 = row0 + mt * 16 + lq * 4;
                union { ushort4 v; unsigned short u[4]; } pk;
                #pragma unroll
                for (int r = 0; r < 4; ++r) {
                    float p1 = acc1[nl][mt][r] + bias1[nl];
                    float p2 = acc2[nl][mt][r] + bias2[nl];
                    pk.u[r] = f2bfbits(sig_gate(p1, p2));
                }
                *(ushort4*)(OUT + (size_t)n * MM + m0) = pk.v;
            }
        }

        // commit prefetched tile LAST: maximizes load-latency cover.
        if (tt + 1 < T) {
            #pragma unroll
            for (int it = 0; it < 2; ++it) {
                int chunk = it * 512 + t;
                int r = chunk >> 4, o = (chunk & 15) << 3;
                pf[it].commit(&xs[cur ^ 1][r][o]);
            }
        }
    }
}

// ---------------------------------------------------------------------------
// K2: per-channel batched GEMM  tri[c] = L_c (512x512) @ R_c^T (512x512)
// R8: EXACT round-0 structure — 95us, FETCH 199MB, WRITE 131MB, VGPR 88,
// occupancy 19% (proven in rounds 0 and 2). DO NOT MODIFY without holding
// FETCH/WRITE/occupancy constant: three pipelining attempts failed via
// (a) XCD-swizzle write concentration (R4: WRITE 3x), (b) 1-barrier desync
// read-reuse decay (R6: FETCH +45MB), (c) reg-prefetch occupancy rise ->
// L2 thrash (R7: FETCH 348MB, WRITE 528MB). The 2-barrier lockstep at
// ~5 blocks/CU IS the L2 locality mechanism.
// ---------------------------------------------------------------------------
template<typename TriT>
__global__ __launch_bounds__(256) void tri_mm_kernel(
    const bf16* __restrict__ Lt, const bf16* __restrict__ Rt,
    TriT* __restrict__ tri)
{
    __shared__ bf16 As[128][40];          // +8 bf16 pad: 80B row stride
    __shared__ bf16 Bs[128][40];
    const int c  = blockIdx.z;
    const int i0 = blockIdx.x * 128, j0 = blockIdx.y * 128;
    const bf16* Lb = Lt + (size_t)c * MM;
    const bf16* Rb = Rt + (size_t)c * MM;

    const int t    = threadIdx.x;
    const int wave = t >> 6, lane = t & 63;
    const int lrow = lane & 15, lq = lane >> 4;
    const int wi = (wave & 1) * 64, wj = (wave >> 1) * 64;

    f32x4 acc[4][4];
    const f32x4 z = {0.f, 0.f, 0.f, 0.f};
    #pragma unroll
    for (int mt = 0; mt < 4; ++mt)
        #pragma unroll
        for (int nt = 0; nt < 4; ++nt) acc[mt][nt] = z;

    for (int k0 = 0; k0 < LL; k0 += 32) {
        __syncthreads();
        #pragma unroll
        for (int it = 0; it < 2; ++it) {
            int chunk = it * 256 + t;
            int r = chunk >> 2, o = (chunk & 3) << 3;
            *(uint4*)(&As[r][o]) = *(const uint4*)(Lb + (size_t)(i0 + r) * LL + k0 + o);
            *(uint4*)(&Bs[r][o]) = *(const uint4*)(Rb + (size_t)(j0 + r) * LL + k0 + o);
        }
        __syncthreads();

        bf16x8 af[4], bfr[4];
        #pragma unroll
        for (int mt = 0; mt < 4; ++mt)
            af[mt] = *(const bf16x8*)(&As[wi + mt * 16 + lrow][lq * 8]);
        #pragma unroll
        for (int nt = 0; nt < 4; ++nt)
            bfr[nt] = *(const bf16x8*)(&Bs[wj + nt * 16 + lrow][lq * 8]);
        #pragma unroll
        for (int mt = 0; mt < 4; ++mt)
            #pragma unroll
            for (int nt = 0; nt < 4; ++nt)
                acc[mt][nt] = __builtin_amdgcn_mfma_f32_16x16x32_bf16(
                    af[mt], bfr[nt], acc[mt][nt], 0, 0, 0);
    }

    TriT* triC = tri + (size_t)c * MM;
    #pragma unroll
    for (int mt = 0; mt < 4; ++mt) {
        #pragma unroll
        for (int nt = 0; nt < 4; ++nt) {
            const int ib = i0 + wi + mt * 16 + lq * 4;
            const int j  = j0 + wj + nt * 16 + lrow;
            #pragma unroll
            for (int r = 0; r < 4; ++r)
                storeT(&triC[(size_t)(ib + r) * LL + j], acc[mt][nt][r]);
        }
    }
}

// ---------------------------------------------------------------------------
// K3: FUSED LayerNorm + output gating. (R6 structure, kept.)
// ---------------------------------------------------------------------------
template<typename TriT>
__global__ __launch_bounds__(256, 2) void ln_gate_kernel(
    const TriT* __restrict__ tri,
    const float* __restrict__ G, const float* __restrict__ Bt,
    const bf16* __restrict__ W1, const float* __restrict__ B1,
    const bf16* __restrict__ W2, const float* __restrict__ B2,
    float* __restrict__ OUT)
{
    __shared__ float s[128][68];          // tri tile [c][p], 272B row stride
    __shared__ bf16 xs[64][136];          // normalized bf16 tile [p][c]
    __shared__ float part[2][4][64];
    __shared__ float mu[64], rsd[64];
    __shared__ float gs[128], bs[128];

    const int t = threadIdx.x;
    const int wave = t >> 6, lane = t & 63;
    const int lrow = lane & 15, lq = lane >> 4;
    const int n0 = wave * 32 + lrow;

    if (t < 128) { gs[t] = G[t]; bs[t] = Bt[t]; }

    bf16x8 wf1[2][4], wf2[2][4];
    float bias1[2], bias2[2];
    #pragma unroll
    for (int nl = 0; nl < 2; ++nl) {
        const int n = n0 + nl * 16;
        bias1[nl] = B1[n]; bias2[nl] = B2[n];
        #pragma unroll
        for (int kk = 0; kk < 4; ++kk) {
            wf1[nl][kk] = *(const bf16x8*)(W1 + n * CC + kk * 32 + lq * 8);
            wf2[nl][kk] = *(const bf16x8*)(W2 + n * CC + kk * 32 + lq * 8);
        }
    }

    constexpr int T = 4;
    const size_t bp0 = (size_t)blockIdx.x * (64 * T);

    // prologue: stage tri tile 0 (128c x 64p fp32 -> s)
    #pragma unroll
    for (int it = 0; it < 8; ++it) {
        int idx = it * 256 + t;
        int cc = idx >> 4, p4 = (idx & 15) << 2;
        float4 f = load4(tri + (size_t)cc * MM + bp0 + p4);
        *(float4*)(&s[cc][p4]) = f;
    }

    for (int tt = 0; tt < T; ++tt) {
        const size_t p0 = bp0 + (size_t)tt * 64;

        float4 pf[8];
        if (tt + 1 < T) {
            #pragma unroll
            for (int it = 0; it < 8; ++it) {
                int idx = it * 256 + t;
                int cc = idx >> 4, p4 = (idx & 15) << 2;
                pf[it] = load4(tri + (size_t)cc * MM + p0 + 64 + p4);
            }
        }
        __syncthreads();   // (a) s staged (prologue or prev commit); gs/bs ready

        // LN stats: wave w sums channels [w*32, w*32+32) at position=lane
        float sum = 0.f, sq = 0.f;
        #pragma unroll 8
        for (int cc = wave * 32; cc < wave * 32 + 32; ++cc) {
            float v = s[cc][lane]; sum += v; sq += v * v;
        }
        part[0][wave][lane] = sum; part[1][wave][lane] = sq;
        __syncthreads();   // (b)
        if (t < 64) {
            float S = part[0][0][t] + part[0][1][t] + part[0][2][t] + part[0][3][t];
            float Q = part[1][0][t] + part[1][1][t] + part[1][2][t] + part[1][3][t];
            float m = S * (1.f / 128.f);
            float var = Q * (1.f / 128.f) - m * m;
            mu[t] = m; rsd[t] = rsqrtf(var + 1e-5f);
        }
        __syncthreads();   // (c)

        // normalize -> xs bf16. p = lane (conflict-free s reads), c8 uniform.
        #pragma unroll
        for (int it = 0; it < 4; ++it) {
            int chunk = it * 256 + t;
            int p = chunk & 63, c8 = (chunk >> 6) << 3;
            float m = mu[p], r = rsd[p];
            union { uint4 v; unsigned short u[8]; } pk;
            #pragma unroll
            for (int jj = 0; jj < 8; ++jj) {
                int cc = c8 + jj;
                pk.u[jj] = f2bfbits((s[cc][p] - m) * r * gs[cc] + bs[cc]);
            }
            *(uint4*)(&xs[p][c8]) = pk.v;
        }
        __syncthreads();   // (d) xs ready; all s reads done

        if (tt + 1 < T) {
            #pragma unroll
            for (int it = 0; it < 8; ++it) {
                int idx = it * 256 + t;
                int cc = idx >> 4, p4 = (idx & 15) << 2;
                *(float4*)(&s[cc][p4]) = pf[it];
            }
        }

        f32x4 acc1[2][4], acc2[2][4];
        const f32x4 z = {0.f, 0.f, 0.f, 0.f};
        #pragma unroll
        for (int nl = 0; nl < 2; ++nl)
            #pragma unroll
            for (int mt = 0; mt < 4; ++mt) { acc1[nl][mt] = z; acc2[nl][mt] = z; }

        #pragma unroll
        for (int kk = 0; kk < 4; ++kk) {
            bf16x8 a[4];
            #pragma unroll
            for (int mt = 0; mt < 4; ++mt)
                a[mt] = *(const bf16x8*)(&xs[mt * 16 + lrow][kk * 32 + lq * 8]);
            #pragma unroll
            for (int nl = 0; nl < 2; ++nl)
                #pragma unroll
                for (int mt = 0; mt < 4; ++mt) {
                    acc1[nl][mt] = __builtin_amdgcn_mfma_f32_16x16x32_bf16(
                        a[mt], wf1[nl][kk], acc1[nl][mt], 0, 0, 0);
                    acc2[nl][mt] = __builtin_amdgcn_mfma_f32_16x16x32_bf16(
                        a[mt], wf2[nl][kk], acc2[nl][mt], 0, 0, 0);
                }
        }

        // epilogue: fp32 out [M][128]
        #pragma unroll
        for (int nl = 0; nl < 2; ++nl) {
            const int n = n0 + nl * 16;
            #pragma unroll
            for (int mt = 0; mt < 4; ++mt) {
                const size_t m0 = p0 + mt * 16 + lq * 4;
                #pragma unroll
                for (int r = 0; r < 4; ++r) {
                    float p1 = acc1[nl][mt][r] + bias1[nl];
                    float p2 = acc2[nl][mt][r] + bias2[nl];
                    OUT[(m0 + r) * CC + n] = sig_gate(p1, p2);
                }
            }
        }
    }
}

// ---------------------------------------------------------------------------
extern "C" void kernel_launch(void* const* d_in, const int* in_sizes, int n_in,
                              void* d_out, int out_size, void* d_ws, size_t ws_size,
                              hipStream_t stream)
{
    const float* x   = (const float*)d_in[0];
    const float* Wl1 = (const float*)d_in[1];
    const float* bl1 = (const float*)d_in[2];
    const float* Wl2 = (const float*)d_in[3];
    const float* bl2 = (const float*)d_in[4];
    const float* Wr1 = (const float*)d_in[5];
    const float* br1 = (const float*)d_in[6];
    const float* Wr2 = (const float*)d_in[7];
    const float* br2 = (const float*)d_in[8];
    const float* Wg  = (const float*)d_in[9];
    const float* bg  = (const float*)d_in[10];
    const float* Wo  = (const float*)d_in[11];
    const float* bo  = (const float*)d_in[12];
    const float* lng = (const float*)d_in[13];
    const float* lnb = (const float*)d_in[14];
    float* out = (float*)d_out;

    char* ws = (char*)d_ws;
    bf16* left_t  = (bf16*)(ws);                        // 64 MiB bf16 [128][M]
    bf16* right_t = (bf16*)(ws + (64ull << 20));        // 64 MiB bf16 [128][M]
    bf16* Wb      = (bf16*)(ws + (128ull << 20));       // 192 KiB: 6 bf16 weights
    void* tri     = (void*)(ws + (132ull << 20));       // 128 MiB fp32 / 64 MiB bf16

    const bool tri_fp32 = (ws_size >= (260ull << 20));

    bf16* Wbg = Wb + 4 * CC * CC;
    bf16* Wbo = Wb + 5 * CC * CC;

    dim3 blk(256);
    cvt_w_kernel<<<dim3(16, 6), blk, 0, stream>>>(Wl1, Wl2, Wr1, Wr2, Wg, Wo, Wb);
    proj_lr_kernel<<<dim3(MM / 256), dim3(512), 0, stream>>>(
        x, Wb, bl1, bl2, br1, br2, left_t, right_t);
    if (tri_fp32) {
        tri_mm_kernel<float><<<dim3(4, 4, 128), blk, 0, stream>>>(left_t, right_t, (float*)tri);
        ln_gate_kernel<float><<<dim3(MM / 256), blk, 0, stream>>>(
            (const float*)tri, lng, lnb, Wbg, bg, Wbo, bo, out);
    } else {
        tri_mm_kernel<bf16><<<dim3(4, 4, 128), blk, 0, stream>>>(left_t, right_t, (bf16*)tri);
        ln_gate_kernel<bf16><<<dim3(MM / 256), blk, 0, stream>>>(
            (const bf16*)tri, lng, lnb, Wbg, bg, Wbo, bo, out);
    }
}

// Round 6
// 430.990 us; speedup vs baseline: 1.3145x; 1.0496x over previous
//
#include <hip/hip_runtime.h>
#include <hip/hip_bf16.h>

#define LL 512
#define CC 128
#define MM (LL*LL)   // 262144 positions

typedef __attribute__((ext_vector_type(8))) short bf16x8;
typedef __attribute__((ext_vector_type(4))) float f32x4;
using bf16 = __hip_bfloat16;

__device__ __forceinline__ unsigned short f2bfbits(float f) {
    bf16 h = __float2bfloat16(f);
    return *reinterpret_cast<unsigned short*>(&h);
}
__device__ __forceinline__ float bfbits2f(unsigned short b) {
    union { unsigned int u; float f; } cv; cv.u = ((unsigned int)b) << 16; return cv.f;
}
__device__ __forceinline__ void storeT(float* p, float v) { *p = v; }
__device__ __forceinline__ void storeT(bf16* p, float v) { *p = __float2bfloat16(v); }
__device__ __forceinline__ float4 load4(const float* p) { return *(const float4*)p; }
__device__ __forceinline__ float4 load4(const bf16* p) {
    ushort4 u = *(const ushort4*)p;
    float4 f;
    f.x = bfbits2f(u.x); f.y = bfbits2f(u.y);
    f.z = bfbits2f(u.z); f.w = bfbits2f(u.w);
    return f;
}

// sigmoid-gate: v * sigmoid(g), with v_rcp_f32 instead of the ~10-instr
// IEEE divide sequence (rcp ~1ulp; downstream rounds to bf16/fp32 — safe).
__device__ __forceinline__ float sig_gate(float g, float v) {
    return v * __builtin_amdgcn_rcpf(1.f + __expf(-g));
}

// stage 8 consecutive fp32 elements into bf16 LDS (16B dst)
__device__ __forceinline__ void stage8(const float* src, bf16* dst) {
    float4 f0 = *(const float4*)(src);
    float4 f1 = *(const float4*)(src + 4);
    union { ushort4 v; unsigned short u[4]; } a, b;
    a.u[0] = f2bfbits(f0.x); a.u[1] = f2bfbits(f0.y);
    a.u[2] = f2bfbits(f0.z); a.u[3] = f2bfbits(f0.w);
    b.u[0] = f2bfbits(f1.x); b.u[1] = f2bfbits(f1.y);
    b.u[2] = f2bfbits(f1.z); b.u[3] = f2bfbits(f1.w);
    *(ushort4*)(dst)     = a.v;
    *(ushort4*)(dst + 4) = b.v;
}

// raw prefetch holder: load global fp32 early, convert/commit to LDS late
struct Raw8F {
    float4 a, b;
    __device__ __forceinline__ void load(const float* p) {
        a = *(const float4*)p; b = *(const float4*)(p + 4);
    }
    __device__ __forceinline__ void commit(bf16* d) const {
        union { ushort4 v; unsigned short u[4]; } x, y;
        x.u[0] = f2bfbits(a.x); x.u[1] = f2bfbits(a.y);
        x.u[2] = f2bfbits(a.z); x.u[3] = f2bfbits(a.w);
        y.u[0] = f2bfbits(b.x); y.u[1] = f2bfbits(b.y);
        y.u[2] = f2bfbits(b.z); y.u[3] = f2bfbits(b.w);
        *(ushort4*)(d)     = x.v;
        *(ushort4*)(d + 4) = y.v;
    }
};

// ---------------------------------------------------------------------------
// K0: convert six 128x128 fp32 weight matrices to bf16 in ws.
// ---------------------------------------------------------------------------
__global__ __launch_bounds__(256) void cvt_w_kernel(
    const float* __restrict__ s0, const float* __restrict__ s1,
    const float* __restrict__ s2, const float* __restrict__ s3,
    const float* __restrict__ s4, const float* __restrict__ s5,
    bf16* __restrict__ dst)
{
    const float* srcs[6] = {s0, s1, s2, s3, s4, s5};
    const float* s = srcs[blockIdx.y];
    bf16* d = dst + blockIdx.y * (CC * CC);
    int i = (blockIdx.x * 256 + threadIdx.x) * 4;
    float4 f = *(const float4*)(s + i);
    union { ushort4 v; unsigned short u[4]; } p;
    p.u[0] = f2bfbits(f.x); p.u[1] = f2bfbits(f.y);
    p.u[2] = f2bfbits(f.z); p.u[3] = f2bfbits(f.w);
    *(ushort4*)(d + i) = p.v;
}

// ---------------------------------------------------------------------------
// K1: dual-GEMM sigmoid-gate projection, 256-thread blocks, grid (1024, 2).
// blockIdx.y selects side (0=left Wl1/Wl2 -> OUTL^T, 1=right -> OUTR^T).
// R9: split from the 512-thread fused block. Rationale: VGPR 92 + 64 AGPR
// = 156/wave -> 3 waves/SIMD -> an 8-wave block was the ONLY resident
// block per CU (occ ~20%), so every barrier/vmcnt drain idled the CU.
// 4-wave blocks co-schedule 3/CU -> cross-block overlap. x (134MB) fits in
// L3, so the second side's re-read is L3-served (round-2: FETCH 68 of 134).
// Per-wave math identical to proven structure; R6 ordering kept (issue
// loads after barrier, commit after epilogue, rcp sigmoid).
// ---------------------------------------------------------------------------
__global__ __launch_bounds__(256, 2) void proj_lr_kernel(
    const float* __restrict__ X, const bf16* __restrict__ Wb,
    const float* __restrict__ Bl1, const float* __restrict__ Bl2,
    const float* __restrict__ Br1, const float* __restrict__ Br2,
    bf16* __restrict__ OUTL, bf16* __restrict__ OUTR)
{
    __shared__ bf16 xs[2][64][136];       // +8 bf16 pad: 272B row stride
    const int t = threadIdx.x;
    const int wave = t >> 6, lane = t & 63;
    const int grp = blockIdx.y;           // 0 = left, 1 = right
    const int lrow = lane & 15, lq = lane >> 4;
    const int n0 = wave * 32 + lrow;      // 4 waves x 32 cols = 128 cols

    const bf16* W1 = Wb + (grp ? 2 * CC * CC : 0);
    const bf16* W2 = W1 + CC * CC;
    const float* B1 = grp ? Br1 : Bl1;
    const float* B2 = grp ? Br2 : Bl2;
    bf16* OUT = grp ? OUTR : OUTL;

    bf16x8 wf1[2][4], wf2[2][4];          // [nt_local][k0/32]
    float bias1[2], bias2[2];
    #pragma unroll
    for (int nl = 0; nl < 2; ++nl) {
        const int n = n0 + nl * 16;
        bias1[nl] = B1[n]; bias2[nl] = B2[n];
        #pragma unroll
        for (int kk = 0; kk < 4; ++kk) {
            wf1[nl][kk] = *(const bf16x8*)(W1 + n * CC + kk * 32 + lq * 8);
            wf2[nl][kk] = *(const bf16x8*)(W2 + n * CC + kk * 32 + lq * 8);
        }
    }

    constexpr int T = 4;
    const size_t block_row0 = (size_t)blockIdx.x * (64 * T);

    // stage tile 0 directly (8192 elements / 256 threads = 4 chunks of 8)
    #pragma unroll
    for (int it = 0; it < 4; ++it) {
        int chunk = it * 256 + t;
        int r = chunk >> 4, o = (chunk & 15) << 3;
        stage8(X + (block_row0 + r) * CC + o, &xs[0][r][o]);
    }

    #pragma unroll
    for (int tt = 0; tt < T; ++tt) {
        const size_t row0 = block_row0 + (size_t)tt * 64;
        const int cur = tt & 1;

        __syncthreads();   // xs[cur] staged; xs[cur^1] readers done

        // issue next tile's loads AFTER the barrier: they stay in flight
        // through MFMA + epilogue; vmcnt wait lands at commit() below.
        Raw8F pf[4];
        if (tt + 1 < T) {
            #pragma unroll
            for (int it = 0; it < 4; ++it) {
                int chunk = it * 256 + t;
                int r = chunk >> 4, o = (chunk & 15) << 3;
                pf[it].load(X + (row0 + 64 + r) * CC + o);
            }
        }

        f32x4 acc1[2][4], acc2[2][4];     // [nt_local][mt]
        const f32x4 z = {0.f, 0.f, 0.f, 0.f};
        #pragma unroll
        for (int nl = 0; nl < 2; ++nl)
            #pragma unroll
            for (int mt = 0; mt < 4; ++mt) { acc1[nl][mt] = z; acc2[nl][mt] = z; }

        #pragma unroll
        for (int kk = 0; kk < 4; ++kk) {
            bf16x8 a[4];
            #pragma unroll
            for (int mt = 0; mt < 4; ++mt)
                a[mt] = *(const bf16x8*)(&xs[cur][mt * 16 + lrow][kk * 32 + lq * 8]);
            #pragma unroll
            for (int nl = 0; nl < 2; ++nl)
                #pragma unroll
                for (int mt = 0; mt < 4; ++mt) {
                    acc1[nl][mt] = __builtin_amdgcn_mfma_f32_16x16x32_bf16(
                        a[mt], wf1[nl][kk], acc1[nl][mt], 0, 0, 0);
                    acc2[nl][mt] = __builtin_amdgcn_mfma_f32_16x16x32_bf16(
                        a[mt], wf2[nl][kk], acc2[nl][mt], 0, 0, 0);
                }
        }

        // epilogue: transposed bf16 store. C/D: col=lane&15 (n), row=lq*4+reg (m)
        #pragma unroll
        for (int nl = 0; nl < 2; ++nl) {
            const int n = n0 + nl * 16;
            #pragma unroll
            for (int mt = 0; mt < 4; ++mt) {
                const size_t m0 = row0 + mt * 16 + lq * 4;
                union { ushort4 v; unsigned short u[4]; } pk;
                #pragma unroll
                for (int r = 0; r < 4; ++r) {
                    float p1 = acc1[nl][mt][r] + bias1[nl];
                    float p2 = acc2[nl][mt][r] + bias2[nl];
                    pk.u[r] = f2bfbits(sig_gate(p1, p2));
                }
                *(ushort4*)(OUT + (size_t)n * MM + m0) = pk.v;
            }
        }

        // commit prefetched tile LAST: maximizes load-latency cover.
        if (tt + 1 < T) {
            #pragma unroll
            for (int it = 0; it < 4; ++it) {
                int chunk = it * 256 + t;
                int r = chunk >> 4, o = (chunk & 15) << 3;
                pf[it].commit(&xs[cur ^ 1][r][o]);
            }
        }
    }
}

// ---------------------------------------------------------------------------
// K2: per-channel batched GEMM  tri[c] = L_c (512x512) @ R_c^T (512x512)
// LOCKED round-0 structure — 95-99us, FETCH ~200MB, WRITE=ideal, VGPR 88,
// occupancy ~18% (proven rounds 0/2/5). DO NOT MODIFY the loop/grid:
// three pipelining attempts failed via (a) XCD-swizzle write concentration
// (R4: WRITE 3x), (b) 1-barrier desync read-reuse decay (R6: FETCH +45MB),
// (c) reg-prefetch occupancy rise -> L2 thrash (R7: WRITE 4x). The
// 2-barrier lockstep at ~5 blocks/CU IS the L2 locality mechanism.
// R9: output dtype bf16 (TriT) — halves tri WRITE and ln_gate's read.
// ---------------------------------------------------------------------------
template<typename TriT>
__global__ __launch_bounds__(256) void tri_mm_kernel(
    const bf16* __restrict__ Lt, const bf16* __restrict__ Rt,
    TriT* __restrict__ tri)
{
    __shared__ bf16 As[128][40];          // +8 bf16 pad: 80B row stride
    __shared__ bf16 Bs[128][40];
    const int c  = blockIdx.z;
    const int i0 = blockIdx.x * 128, j0 = blockIdx.y * 128;
    const bf16* Lb = Lt + (size_t)c * MM;
    const bf16* Rb = Rt + (size_t)c * MM;

    const int t    = threadIdx.x;
    const int wave = t >> 6, lane = t & 63;
    const int lrow = lane & 15, lq = lane >> 4;
    const int wi = (wave & 1) * 64, wj = (wave >> 1) * 64;

    f32x4 acc[4][4];
    const f32x4 z = {0.f, 0.f, 0.f, 0.f};
    #pragma unroll
    for (int mt = 0; mt < 4; ++mt)
        #pragma unroll
        for (int nt = 0; nt < 4; ++nt) acc[mt][nt] = z;

    for (int k0 = 0; k0 < LL; k0 += 32) {
        __syncthreads();
        #pragma unroll
        for (int it = 0; it < 2; ++it) {
            int chunk = it * 256 + t;
            int r = chunk >> 2, o = (chunk & 3) << 3;
            *(uint4*)(&As[r][o]) = *(const uint4*)(Lb + (size_t)(i0 + r) * LL + k0 + o);
            *(uint4*)(&Bs[r][o]) = *(const uint4*)(Rb + (size_t)(j0 + r) * LL + k0 + o);
        }
        __syncthreads();

        bf16x8 af[4], bfr[4];
        #pragma unroll
        for (int mt = 0; mt < 4; ++mt)
            af[mt] = *(const bf16x8*)(&As[wi + mt * 16 + lrow][lq * 8]);
        #pragma unroll
        for (int nt = 0; nt < 4; ++nt)
            bfr[nt] = *(const bf16x8*)(&Bs[wj + nt * 16 + lrow][lq * 8]);
        #pragma unroll
        for (int mt = 0; mt < 4; ++mt)
            #pragma unroll
            for (int nt = 0; nt < 4; ++nt)
                acc[mt][nt] = __builtin_amdgcn_mfma_f32_16x16x32_bf16(
                    af[mt], bfr[nt], acc[mt][nt], 0, 0, 0);
    }

    TriT* triC = tri + (size_t)c * MM;
    #pragma unroll
    for (int mt = 0; mt < 4; ++mt) {
        #pragma unroll
        for (int nt = 0; nt < 4; ++nt) {
            const int ib = i0 + wi + mt * 16 + lq * 4;
            const int j  = j0 + wj + nt * 16 + lrow;
            #pragma unroll
            for (int r = 0; r < 4; ++r)
                storeT(&triC[(size_t)(ib + r) * LL + j], acc[mt][nt][r]);
        }
    }
}

// ---------------------------------------------------------------------------
// K3: FUSED LayerNorm + output gating. (R6 structure.)
// R9: reads bf16 tri (load4 converts) — FETCH halves on the tri stream.
// ---------------------------------------------------------------------------
template<typename TriT>
__global__ __launch_bounds__(256, 2) void ln_gate_kernel(
    const TriT* __restrict__ tri,
    const float* __restrict__ G, const float* __restrict__ Bt,
    const bf16* __restrict__ W1, const float* __restrict__ B1,
    const bf16* __restrict__ W2, const float* __restrict__ B2,
    float* __restrict__ OUT)
{
    __shared__ float s[128][68];          // tri tile [c][p], 272B row stride
    __shared__ bf16 xs[64][136];          // normalized bf16 tile [p][c]
    __shared__ float part[2][4][64];
    __shared__ float mu[64], rsd[64];
    __shared__ float gs[128], bs[128];

    const int t = threadIdx.x;
    const int wave = t >> 6, lane = t & 63;
    const int lrow = lane & 15, lq = lane >> 4;
    const int n0 = wave * 32 + lrow;

    if (t < 128) { gs[t] = G[t]; bs[t] = Bt[t]; }

    bf16x8 wf1[2][4], wf2[2][4];
    float bias1[2], bias2[2];
    #pragma unroll
    for (int nl = 0; nl < 2; ++nl) {
        const int n = n0 + nl * 16;
        bias1[nl] = B1[n]; bias2[nl] = B2[n];
        #pragma unroll
        for (int kk = 0; kk < 4; ++kk) {
            wf1[nl][kk] = *(const bf16x8*)(W1 + n * CC + kk * 32 + lq * 8);
            wf2[nl][kk] = *(const bf16x8*)(W2 + n * CC + kk * 32 + lq * 8);
        }
    }

    constexpr int T = 4;
    const size_t bp0 = (size_t)blockIdx.x * (64 * T);

    // prologue: stage tri tile 0 (128c x 64p -> s)
    #pragma unroll
    for (int it = 0; it < 8; ++it) {
        int idx = it * 256 + t;
        int cc = idx >> 4, p4 = (idx & 15) << 2;
        float4 f = load4(tri + (size_t)cc * MM + bp0 + p4);
        *(float4*)(&s[cc][p4]) = f;
    }

    for (int tt = 0; tt < T; ++tt) {
        const size_t p0 = bp0 + (size_t)tt * 64;

        float4 pf[8];
        if (tt + 1 < T) {
            #pragma unroll
            for (int it = 0; it < 8; ++it) {
                int idx = it * 256 + t;
                int cc = idx >> 4, p4 = (idx & 15) << 2;
                pf[it] = load4(tri + (size_t)cc * MM + p0 + 64 + p4);
            }
        }
        __syncthreads();   // (a) s staged (prologue or prev commit); gs/bs ready

        // LN stats: wave w sums channels [w*32, w*32+32) at position=lane
        float sum = 0.f, sq = 0.f;
        #pragma unroll 8
        for (int cc = wave * 32; cc < wave * 32 + 32; ++cc) {
            float v = s[cc][lane]; sum += v; sq += v * v;
        }
        part[0][wave][lane] = sum; part[1][wave][lane] = sq;
        __syncthreads();   // (b)
        if (t < 64) {
            float S = part[0][0][t] + part[0][1][t] + part[0][2][t] + part[0][3][t];
            float Q = part[1][0][t] + part[1][1][t] + part[1][2][t] + part[1][3][t];
            float m = S * (1.f / 128.f);
            float var = Q * (1.f / 128.f) - m * m;
            mu[t] = m; rsd[t] = rsqrtf(var + 1e-5f);
        }
        __syncthreads();   // (c)

        // normalize -> xs bf16. p = lane (conflict-free s reads), c8 uniform.
        #pragma unroll
        for (int it = 0; it < 4; ++it) {
            int chunk = it * 256 + t;
            int p = chunk & 63, c8 = (chunk >> 6) << 3;
            float m = mu[p], r = rsd[p];
            union { uint4 v; unsigned short u[8]; } pk;
            #pragma unroll
            for (int jj = 0; jj < 8; ++jj) {
                int cc = c8 + jj;
                pk.u[jj] = f2bfbits((s[cc][p] - m) * r * gs[cc] + bs[cc]);
            }
            *(uint4*)(&xs[p][c8]) = pk.v;
        }
        __syncthreads();   // (d) xs ready; all s reads done

        if (tt + 1 < T) {
            #pragma unroll
            for (int it = 0; it < 8; ++it) {
                int idx = it * 256 + t;
                int cc = idx >> 4, p4 = (idx & 15) << 2;
                *(float4*)(&s[cc][p4]) = pf[it];
            }
        }

        f32x4 acc1[2][4], acc2[2][4];
        const f32x4 z = {0.f, 0.f, 0.f, 0.f};
        #pragma unroll
        for (int nl = 0; nl < 2; ++nl)
            #pragma unroll
            for (int mt = 0; mt < 4; ++mt) { acc1[nl][mt] = z; acc2[nl][mt] = z; }

        #pragma unroll
        for (int kk = 0; kk < 4; ++kk) {
            bf16x8 a[4];
            #pragma unroll
            for (int mt = 0; mt < 4; ++mt)
                a[mt] = *(const bf16x8*)(&xs[mt * 16 + lrow][kk * 32 + lq * 8]);
            #pragma unroll
            for (int nl = 0; nl < 2; ++nl)
                #pragma unroll
                for (int mt = 0; mt < 4; ++mt) {
                    acc1[nl][mt] = __builtin_amdgcn_mfma_f32_16x16x32_bf16(
                        a[mt], wf1[nl][kk], acc1[nl][mt], 0, 0, 0);
                    acc2[nl][mt] = __builtin_amdgcn_mfma_f32_16x16x32_bf16(
                        a[mt], wf2[nl][kk], acc2[nl][mt], 0, 0, 0);
                }
        }

        // epilogue: fp32 out [M][128]
        #pragma unroll
        for (int nl = 0; nl < 2; ++nl) {
            const int n = n0 + nl * 16;
            #pragma unroll
            for (int mt = 0; mt < 4; ++mt) {
                const size_t m0 = p0 + mt * 16 + lq * 4;
                #pragma unroll
                for (int r = 0; r < 4; ++r) {
                    float p1 = acc1[nl][mt][r] + bias1[nl];
                    float p2 = acc2[nl][mt][r] + bias2[nl];
                    OUT[(m0 + r) * CC + n] = sig_gate(p1, p2);
                }
            }
        }
    }
}

// ---------------------------------------------------------------------------
extern "C" void kernel_launch(void* const* d_in, const int* in_sizes, int n_in,
                              void* d_out, int out_size, void* d_ws, size_t ws_size,
                              hipStream_t stream)
{
    const float* x   = (const float*)d_in[0];
    const float* Wl1 = (const float*)d_in[1];
    const float* bl1 = (const float*)d_in[2];
    const float* Wl2 = (const float*)d_in[3];
    const float* bl2 = (const float*)d_in[4];
    const float* Wr1 = (const float*)d_in[5];
    const float* br1 = (const float*)d_in[6];
    const float* Wr2 = (const float*)d_in[7];
    const float* br2 = (const float*)d_in[8];
    const float* Wg  = (const float*)d_in[9];
    const float* bg  = (const float*)d_in[10];
    const float* Wo  = (const float*)d_in[11];
    const float* bo  = (const float*)d_in[12];
    const float* lng = (const float*)d_in[13];
    const float* lnb = (const float*)d_in[14];
    float* out = (float*)d_out;

    char* ws = (char*)d_ws;
    bf16* left_t  = (bf16*)(ws);                        // 64 MiB bf16 [128][M]
    bf16* right_t = (bf16*)(ws + (64ull << 20));        // 64 MiB bf16 [128][M]
    bf16* Wb      = (bf16*)(ws + (128ull << 20));       // 192 KiB: 6 bf16 weights
    bf16* tri     = (bf16*)(ws + (132ull << 20));       // 64 MiB bf16 [128][M]

    bf16* Wbg = Wb + 4 * CC * CC;
    bf16* Wbo = Wb + 5 * CC * CC;

    dim3 blk(256);
    cvt_w_kernel<<<dim3(16, 6), blk, 0, stream>>>(Wl1, Wl2, Wr1, Wr2, Wg, Wo, Wb);
    proj_lr_kernel<<<dim3(MM / 256, 2), blk, 0, stream>>>(
        x, Wb, bl1, bl2, br1, br2, left_t, right_t);
    tri_mm_kernel<bf16><<<dim3(4, 4, 128), blk, 0, stream>>>(left_t, right_t, tri);
    ln_gate_kernel<bf16><<<dim3(MM / 256), blk, 0, stream>>>(
        (const bf16*)tri, lng, lnb, Wbg, bg, Wbo, bo, out);
}